// Round 1
// baseline (1055.313 us; speedup 1.0000x reference)
//
#include <hip/hip_runtime.h>
#include <hip/hip_bf16.h>

#define DIM 64
#define TILE_ROWS 64
#define NEG_HUGE (-3.402823466e+38f)

// ---------- comparator / top-3 insert ----------
__device__ __forceinline__ bool better_vi(float v, int i, float v2, int i2) {
    return (v > v2) || (v == v2 && i < i2);
}

// fast path: strictly-greater insert (candidates arrive in ascending index order,
// so strict > implements the lower-index-wins tie-break)
__device__ __forceinline__ void ins3_fast(float s, int idx,
                                          float& v0, int& i0, float& v1, int& i1,
                                          float& v2, int& i2) {
    if (s > v2) {
        if (s > v1) {
            v2 = v1; i2 = i1;
            if (s > v0) { v1 = v0; i1 = i0; v0 = s; i0 = idx; }
            else        { v1 = s;  i1 = idx; }
        } else { v2 = s; i2 = idx; }
    }
}

// comparator insert for merge phase (candidates arrive in arbitrary index order)
__device__ __forceinline__ void ins3_cmp(float s, int idx,
                                         float& v0, int& i0, float& v1, int& i1,
                                         float& v2, int& i2) {
    if (better_vi(s, idx, v2, i2)) {
        if (better_vi(s, idx, v1, i1)) {
            v2 = v1; i2 = i1;
            if (better_vi(s, idx, v0, i0)) { v1 = v0; i1 = i0; v0 = s; i0 = idx; }
            else                            { v1 = s;  i1 = idx; }
        } else { v2 = s; i2 = idx; }
    }
}

// ---------- kernel 0: q_unit = emb / ||emb|| ----------
__global__ void qunit_kernel(const float* __restrict__ emb, float* __restrict__ qu) {
    int b = blockIdx.x, d = threadIdx.x;          // 64 threads/block
    float x = emb[b * DIM + d];
    float s = x * x;
    #pragma unroll
    for (int off = 32; off > 0; off >>= 1) s += __shfl_xor(s, off);
    float inv = (s > 0.f) ? (1.0f / sqrtf(s)) : 1.0f;
    qu[b * DIM + d] = x * inv;
}

// ---------- kernel 1: fused dot + per-block top-3 ----------
// 128 threads/block, 2 queries per thread (B=256 queries total).
__global__ __launch_bounds__(128, 2)
void topk_partial_kernel(const float* __restrict__ kb,
                         const float* __restrict__ qunit,
                         float* __restrict__ tv,   // [256][NB][3]
                         int*   __restrict__ ti,   // [256][NB][3]
                         int NB, int N, int rpb) {
    __shared__ float4 tile4[TILE_ROWS * (DIM / 4)];   // 16 KB
    __shared__ float  rinv[TILE_ROWS];

    const int t   = threadIdx.x;
    const int blk = blockIdx.x;
    const long r0 = (long)blk * rpb;
    const long r1 = min((long)N, r0 + (long)rpb);

    // load 2 query rows into registers (static indexing only)
    const int q0i = 2 * t, q1i = 2 * t + 1;
    const float4* qv = (const float4*)qunit;
    float4 q0[16], q1[16];
    #pragma unroll
    for (int j = 0; j < 16; j++) { q0[j] = qv[q0i * 16 + j]; q1[j] = qv[q1i * 16 + j]; }

    float a0 = NEG_HUGE, a1 = NEG_HUGE, a2 = NEG_HUGE;
    float b0 = NEG_HUGE, b1 = NEG_HUGE, b2 = NEG_HUGE;
    int ai0 = 0, ai1 = 0, ai2 = 0, bi0 = 0, bi1 = 0, bi2 = 0;

    for (long base = r0; base < r1; base += TILE_ROWS) {
        const int valid = (int)min((long)TILE_ROWS, r1 - base);

        // stage 64 rows (1024 float4) with 128 threads: 8 float4 each, coalesced
        const float4* src = (const float4*)kb + base * (DIM / 4);
        const int maxc4 = valid * (DIM / 4);
        #pragma unroll
        for (int j = 0; j < 8; j++) {
            int c  = t + j * 128;
            int cs = (c < maxc4) ? c : 0;
            tile4[c] = src[cs];
        }
        __syncthreads();

        // row inverse norms: 2 threads per row
        {
            int row = t >> 1, half = t & 1;
            const float4* rp = tile4 + row * (DIM / 4) + half * 8;
            float s = 0.f;
            #pragma unroll
            for (int j = 0; j < 8; j++) {
                float4 a = rp[j];
                s += a.x * a.x + a.y * a.y + a.z * a.z + a.w * a.w;
            }
            s += __shfl_xor(s, 1);
            if (half == 0) rinv[row] = (s > 0.f) ? (1.0f / sqrtf(s)) : 1.0f;
        }
        __syncthreads();

        // score rows against both queries (LDS broadcast reads, conflict-free)
        for (int r = 0; r < valid; r++) {
            const float4* rp = tile4 + r * (DIM / 4);
            float4 accA = make_float4(0.f, 0.f, 0.f, 0.f);
            float4 accB = make_float4(0.f, 0.f, 0.f, 0.f);
            #pragma unroll
            for (int j = 0; j < 16; j++) {
                float4 kv = rp[j];
                accA.x += kv.x * q0[j].x; accA.y += kv.y * q0[j].y;
                accA.z += kv.z * q0[j].z; accA.w += kv.w * q0[j].w;
                accB.x += kv.x * q1[j].x; accB.y += kv.y * q1[j].y;
                accB.z += kv.z * q1[j].z; accB.w += kv.w * q1[j].w;
            }
            const float rn = rinv[r];
            const float sA = ((accA.x + accA.y) + (accA.z + accA.w)) * rn;
            const float sB = ((accB.x + accB.y) + (accB.z + accB.w)) * rn;
            const int gidx = (int)(base + r);
            ins3_fast(sA, gidx, a0, ai0, a1, ai1, a2, ai2);
            ins3_fast(sB, gidx, b0, bi0, b1, bi1, b2, bi2);
        }
        __syncthreads();
    }

    // write per-block results: layout [q][NB][3]
    {
        size_t o = ((size_t)q0i * NB + blk) * 3;
        tv[o] = a0; tv[o + 1] = a1; tv[o + 2] = a2;
        ti[o] = ai0; ti[o + 1] = ai1; ti[o + 2] = ai2;
        o = ((size_t)q1i * NB + blk) * 3;
        tv[o] = b0; tv[o + 1] = b1; tv[o + 2] = b2;
        ti[o] = bi0; ti[o + 1] = bi1; ti[o + 2] = bi2;
    }
}

// ---------- kernel 2: merge per-block top-3 -> final top-3 -> context ----------
// one block (64 threads = 1 wave) per query
__global__ void merge_ctx_kernel(const float* __restrict__ tv,
                                 const int*   __restrict__ ti,
                                 const float* __restrict__ kb,
                                 float* __restrict__ ctx_out,  // [256][64]
                                 int NB) {
    const int q = blockIdx.x, lane = threadIdx.x;
    const float* tvq = tv + (size_t)q * NB * 3;
    const int*   tiq = ti + (size_t)q * NB * 3;

    float v0 = NEG_HUGE, v1 = NEG_HUGE, v2 = NEG_HUGE;
    int i0 = 0, i1 = 0, i2 = 0;
    const int total = NB * 3;
    for (int c = lane; c < total; c += 64) {
        ins3_cmp(tvq[c], tiq[c], v0, i0, v1, i1, v2, i2);
    }
    // wave butterfly merge
    #pragma unroll
    for (int off = 1; off < 64; off <<= 1) {
        float w0 = __shfl_xor(v0, off), w1 = __shfl_xor(v1, off), w2 = __shfl_xor(v2, off);
        int   j0 = __shfl_xor(i0, off), j1 = __shfl_xor(i1, off), j2 = __shfl_xor(i2, off);
        ins3_cmp(w0, j0, v0, i0, v1, i1, v2, i2);
        ins3_cmp(w1, j1, v0, i0, v1, i1, v2, i2);
        ins3_cmp(w2, j2, v0, i0, v1, i1, v2, i2);
    }
    // context = mean of the 3 kb rows (summed in rank order, like the reference)
    const int d = lane;
    float c0 = kb[(size_t)i0 * DIM + d];
    float c1 = kb[(size_t)i1 * DIM + d];
    float c2 = kb[(size_t)i2 * DIM + d];
    ctx_out[(size_t)q * DIM + d] = ((c0 + c1) + c2) / 3.0f;
}

// ---------- kernel 3: MLP tail (attn == 1 identically, q/k are dead code) ----------
// one block (128 threads) per batch row
__global__ void mlp_kernel(const float* __restrict__ emb,
                           const float* __restrict__ ctx,
                           const float* __restrict__ in_proj_w,  // (192,64)
                           const float* __restrict__ in_proj_b,  // (192)
                           const float* __restrict__ out_w,      // (64,64)
                           const float* __restrict__ out_b,      // (64)
                           const float* __restrict__ ci_w1,      // (64,128)
                           const float* __restrict__ ci_b1,      // (64)
                           const float* __restrict__ ci_w2,      // (64,64)
                           const float* __restrict__ ci_b2,      // (64)
                           const float* __restrict__ cls_w1,     // (128,64)
                           const float* __restrict__ cls_b1,     // (128)
                           const float* __restrict__ cls_w2,     // (2,128)
                           const float* __restrict__ cls_b2,     // (2)
                           float* __restrict__ pred) {           // (256,2)
    __shared__ float se[64], sc[64], sv[64], sa[64], sh[64], senh[64], scc[128];
    const int b = blockIdx.x, t = threadIdx.x;

    if (t < 64) { se[t] = emb[b * 64 + t]; sc[t] = ctx[b * 64 + t]; }
    __syncthreads();
    if (t < 64) {   // v = ctx @ wv.T + bv
        const float* w = in_proj_w + (size_t)(128 + t) * 64;
        float s = in_proj_b[128 + t];
        #pragma unroll 8
        for (int d = 0; d < 64; d++) s += sc[d] * w[d];
        sv[t] = s;
    }
    __syncthreads();
    if (t < 64) {   // attended = v @ out_w.T + out_b
        const float* w = out_w + (size_t)t * 64;
        float s = out_b[t];
        #pragma unroll 8
        for (int d = 0; d < 64; d++) s += sv[d] * w[d];
        sa[t] = s;
    }
    __syncthreads();
    if (t < 64) {   // h = relu([emb, attended] @ ci_w1.T + ci_b1)
        const float* w = ci_w1 + (size_t)t * 128;
        float s = ci_b1[t];
        #pragma unroll 8
        for (int d = 0; d < 64; d++) s += se[d] * w[d];
        #pragma unroll 8
        for (int d = 0; d < 64; d++) s += sa[d] * w[64 + d];
        sh[t] = fmaxf(s, 0.f);
    }
    __syncthreads();
    if (t < 64) {   // enhanced = h @ ci_w2.T + ci_b2
        const float* w = ci_w2 + (size_t)t * 64;
        float s = ci_b2[t];
        #pragma unroll 8
        for (int d = 0; d < 64; d++) s += sh[d] * w[d];
        senh[t] = s;
    }
    __syncthreads();
    {               // c = relu(enhanced @ cls_w1.T + cls_b1)   (all 128 threads)
        const float* w = cls_w1 + (size_t)t * 64;
        float s = cls_b1[t];
        #pragma unroll 8
        for (int d = 0; d < 64; d++) s += senh[d] * w[d];
        scc[t] = fmaxf(s, 0.f);
    }
    __syncthreads();
    if (t < 2) {    // predictions = c @ cls_w2.T + cls_b2
        const float* w = cls_w2 + (size_t)t * 128;
        float s = cls_b2[t];
        for (int d = 0; d < 128; d++) s += scc[d] * w[d];
        pred[b * 2 + t] = s;
    }
}

extern "C" void kernel_launch(void* const* d_in, const int* in_sizes, int n_in,
                              void* d_out, int out_size, void* d_ws, size_t ws_size,
                              hipStream_t stream) {
    const float* emb       = (const float*)d_in[0];
    const float* kb        = (const float*)d_in[1];
    const float* in_proj_w = (const float*)d_in[2];
    const float* in_proj_b = (const float*)d_in[3];
    const float* out_w     = (const float*)d_in[4];
    const float* out_b     = (const float*)d_in[5];
    const float* ci_w1     = (const float*)d_in[6];
    const float* ci_b1     = (const float*)d_in[7];
    const float* ci_w2     = (const float*)d_in[8];
    const float* ci_b2     = (const float*)d_in[9];
    const float* cls_w1    = (const float*)d_in[10];
    const float* cls_b1    = (const float*)d_in[11];
    const float* cls_w2    = (const float*)d_in[12];
    const float* cls_b2    = (const float*)d_in[13];
    float* out = (float*)d_out;

    const int Bq = in_sizes[0] / DIM;   // 256
    const int N  = in_sizes[1] / DIM;   // 1,000,000

    // workspace layout: [q_unit: Bq*64 f32][tv: Bq*NB*3 f32][ti: Bq*NB*3 i32]
    float* qunit = (float*)d_ws;
    const size_t qunit_bytes = (size_t)Bq * DIM * 4;
    long avail = (long)ws_size - (long)qunit_bytes;
    int NB = (int)(avail / ((long)Bq * 3 * 8));
    if (NB > 1024) NB = 1024;
    if (NB < 1)    NB = 1;
    float* tv = qunit + (size_t)Bq * DIM;
    int*   ti = (int*)(tv + (size_t)Bq * NB * 3);
    const int rpb = (N + NB - 1) / NB;

    float* ctx_out  = out + (size_t)Bq * 2;   // context region of d_out
    float* pred_out = out;

    qunit_kernel<<<Bq, 64, 0, stream>>>(emb, qunit);
    topk_partial_kernel<<<NB, 128, 0, stream>>>(kb, qunit, tv, ti, NB, N, rpb);
    merge_ctx_kernel<<<Bq, 64, 0, stream>>>(tv, ti, kb, ctx_out, NB);
    mlp_kernel<<<Bq, 128, 0, stream>>>(emb, ctx_out, in_proj_w, in_proj_b,
                                       out_w, out_b, ci_w1, ci_b1, ci_w2, ci_b2,
                                       cls_w1, cls_b1, cls_w2, cls_b2, pred_out);
}

// Round 2
// 291.239 us; speedup vs baseline: 3.6235x; 3.6235x over previous
//
#include <hip/hip_runtime.h>
#include <hip/hip_bf16.h>

#define DIM 64
#define NEG_HUGE (-3.402823466e+38f)

typedef __attribute__((ext_vector_type(8))) short bf16x8;
typedef __attribute__((ext_vector_type(4))) float f32x4;

__device__ __forceinline__ unsigned short f2bf(float f) {
    unsigned u = __float_as_uint(f);
    u += 0x7FFFu + ((u >> 16) & 1u);   // round-to-nearest-even
    return (unsigned short)(u >> 16);
}

__device__ __forceinline__ bool better_vi(float v, int i, float v2, int i2) {
    return (v > v2) || (v == v2 && i < i2);
}

__device__ __forceinline__ void ins3_cmp(float s, int idx,
                                         float& v0, int& i0, float& v1, int& i1,
                                         float& v2, int& i2) {
    if (better_vi(s, idx, v2, i2)) {
        if (better_vi(s, idx, v1, i1)) {
            v2 = v1; i2 = i1;
            if (better_vi(s, idx, v0, i0)) { v1 = v0; i1 = i0; v0 = s; i0 = idx; }
            else                            { v1 = s;  i1 = idx; }
        } else { v2 = s; i2 = idx; }
    }
}

// ---------- kernel 0: q_unit = emb / ||emb|| (f32, exact-style like round-1) ----------
__global__ void qunit_kernel(const float* __restrict__ emb, float* __restrict__ qu) {
    int b = blockIdx.x, d = threadIdx.x;          // 64 threads/block
    float x = emb[b * DIM + d];
    float s = x * x;
    #pragma unroll
    for (int off = 32; off > 0; off >>= 1) s += __shfl_xor(s, off);
    float inv = (s > 0.f) ? (1.0f / sqrtf(s)) : 1.0f;
    qu[b * DIM + d] = x * inv;
}

// ---------- kernel 1: bf16-MFMA scoring + per-block approx top-3 ----------
// 256 threads (4 waves). Each wave owns 64 queries (4 query-tiles of 16).
// Per 64-row chunk: stage f32 -> row-normalize -> bf16 -> swizzled LDS,
// then 16x16x32 MFMA scoring with tag-in-mantissa top-2 per (lane,query).
__global__ __launch_bounds__(256, 3)
void score_topk_kernel(const float* __restrict__ kb,
                       const float* __restrict__ qunit,
                       float* __restrict__ tv,   // [256][NB][3] approx values
                       int*   __restrict__ ti,   // [256][NB][3] row indices
                       int NB, int N, int rpb) {
    __shared__ unsigned char ktile[64 * 128];     // 64 rows x 64 bf16, XOR-swizzled

    const int t    = threadIdx.x;
    const int lane = t & 63;
    const int w    = t >> 6;                      // wave 0..3
    const int blk  = blockIdx.x;
    const long r0  = (long)blk * (long)rpb;
    const long r1  = min((long)N, r0 + (long)rpb);

    // ---- A fragments: queries [64w, 64w+64) in bf16, resident in VGPRs ----
    bf16x8 afr[4][2];
    {
        const int qrow = lane & 15;
        const int k0   = (lane >> 4) * 8;
        #pragma unroll
        for (int qt = 0; qt < 4; qt++) {
            int q = (4 * w + qt) * 16 + qrow;
            #pragma unroll
            for (int kh = 0; kh < 2; kh++) {
                const float* src = qunit + (size_t)q * DIM + k0 + kh * 32;
                float4 f0 = *(const float4*)(src);
                float4 f1 = *(const float4*)(src + 4);
                bf16x8 a;
                a[0] = (short)f2bf(f0.x); a[1] = (short)f2bf(f0.y);
                a[2] = (short)f2bf(f0.z); a[3] = (short)f2bf(f0.w);
                a[4] = (short)f2bf(f1.x); a[5] = (short)f2bf(f1.y);
                a[6] = (short)f2bf(f1.z); a[7] = (short)f2bf(f1.w);
                afr[qt][kh] = a;
            }
        }
    }

    // per-(lane,query) top-2 tagged scores: v1 = best, v2 = second
    float v1[4][4], v2[4][4];
    #pragma unroll
    for (int a = 0; a < 4; a++)
        #pragma unroll
        for (int b = 0; b < 4; b++) { v1[a][b] = NEG_HUGE; v2[a][b] = NEG_HUGE; }

    long drows = r1 - r0;
    const int nch = (drows > 0) ? (int)((drows + 63) >> 6) : 0;   // <= 64 (8-bit tag)

    // prefetch chunk 0 (global -> regs)
    float4 ld[4];
    #pragma unroll
    for (int j = 0; j < 4; j++) {
        int f4 = t + 256 * j;
        long vrow = r0 + (f4 >> 4);
        ld[j] = (vrow < r1) ? ((const float4*)kb)[vrow * 16 + (f4 & 15)]
                            : make_float4(0.f, 0.f, 0.f, 0.f);
    }

    for (int c = 0; c < nch; c++) {
        // ---- write phase: row norms (16-lane shuffle reduce), scale, bf16, swizzled ds_write ----
        #pragma unroll
        for (int j = 0; j < 4; j++) {
            float s = ld[j].x * ld[j].x + ld[j].y * ld[j].y
                    + ld[j].z * ld[j].z + ld[j].w * ld[j].w;
            #pragma unroll
            for (int off = 1; off < 16; off <<= 1) s += __shfl_xor(s, off);
            float rinv = (s > 0.f) ? rsqrtf(s) : 1.0f;
            unsigned short h0 = f2bf(ld[j].x * rinv), h1 = f2bf(ld[j].y * rinv);
            unsigned short h2 = f2bf(ld[j].z * rinv), h3 = f2bf(ld[j].w * rinv);
            int row  = (t >> 4) + 16 * j;                     // 0..63
            int col8 = (t & 15) * 8;                          // byte offset of 4 bf16
            int byte = row * 128 + (col8 ^ ((row & 7) << 4)); // XOR swizzle (bits 4-6)
            uint2 pk;
            pk.x = (unsigned)h0 | ((unsigned)h1 << 16);
            pk.y = (unsigned)h2 | ((unsigned)h3 << 16);
            *(uint2*)(ktile + byte) = pk;
        }
        __syncthreads();   // tile ready

        // ---- prefetch next chunk (overlaps MFMA below) ----
        if (c + 1 < nch) {
            long base = r0 + (long)(c + 1) * 64;
            #pragma unroll
            for (int j = 0; j < 4; j++) {
                int f4 = t + 256 * j;
                long vrow = base + (f4 >> 4);
                ld[j] = (vrow < r1) ? ((const float4*)kb)[vrow * 16 + (f4 & 15)]
                                    : make_float4(0.f, 0.f, 0.f, 0.f);
            }
        }

        // ---- score: 4 row-tiles x 4 query-tiles, K=64 in two MFMAs ----
        const int hb   = (lane >> 4) * 16;     // byte col base of b-frag
        const int brow = lane & 15;
        const unsigned tagbase = (unsigned)(c << 2);
        #pragma unroll
        for (int rt = 0; rt < 4; rt++) {
            int row = rt * 16 + brow;
            int sw  = (row & 7) << 4;
            bf16x8 bf0 = *(const bf16x8*)(ktile + row * 128 + ((hb     ) ^ sw));
            bf16x8 bf1 = *(const bf16x8*)(ktile + row * 128 + ((hb + 64) ^ sw));
            const unsigned tag = tagbase | (unsigned)rt;
            #pragma unroll
            for (int qt = 0; qt < 4; qt++) {
                f32x4 acc = {0.f, 0.f, 0.f, 0.f};
                acc = __builtin_amdgcn_mfma_f32_16x16x32_bf16(afr[qt][0], bf0, acc, 0, 0, 0);
                acc = __builtin_amdgcn_mfma_f32_16x16x32_bf16(afr[qt][1], bf1, acc, 0, 0, 0);
                #pragma unroll
                for (int j = 0; j < 4; j++) {
                    float x = acc[j];
                    float xt = __uint_as_float((__float_as_uint(x) & 0xFFFFFF00u) | tag);
                    float mn = fminf(xt, v1[qt][j]);
                    v1[qt][j] = fmaxf(xt, v1[qt][j]);
                    v2[qt][j] = fmaxf(v2[qt][j], mn);
                }
            }
        }
        __syncthreads();   // all reads done before next overwrite
    }

    // ---- reduce: per query, merge 16 lanes x top-2 -> block top-3, write out ----
    #pragma unroll
    for (int qt = 0; qt < 4; qt++) {
        #pragma unroll
        for (int j = 0; j < 4; j++) {
            float bv0 = NEG_HUGE, bv1 = NEG_HUGE, bv2 = NEG_HUGE;
            int   bi0 = 0, bi1 = 0, bi2 = 0;
            #pragma unroll
            for (int s = 0; s < 2; s++) {
                float vv = s ? v2[qt][j] : v1[qt][j];
                if (vv != NEG_HUGE) {
                    unsigned tag = __float_as_uint(vv) & 0xFFu;
                    long row = r0 + (long)(tag >> 2) * 64 + (long)(tag & 3u) * 16 + (lane & 15);
                    if (row < r1) ins3_cmp(vv, (int)row, bv0, bi0, bv1, bi1, bv2, bi2);
                }
            }
            #pragma unroll
            for (int off = 1; off < 16; off <<= 1) {
                float w0 = __shfl_xor(bv0, off), w1 = __shfl_xor(bv1, off), w2 = __shfl_xor(bv2, off);
                int   x0 = __shfl_xor(bi0, off), x1 = __shfl_xor(bi1, off), x2 = __shfl_xor(bi2, off);
                ins3_cmp(w0, x0, bv0, bi0, bv1, bi1, bv2, bi2);
                ins3_cmp(w1, x1, bv0, bi0, bv1, bi1, bv2, bi2);
                ins3_cmp(w2, x2, bv0, bi0, bv1, bi1, bv2, bi2);
            }
            if ((lane & 15) == 0) {
                int q = (4 * w + qt) * 16 + (lane >> 4) * 4 + j;
                size_t o = ((size_t)q * NB + blk) * 3;
                tv[o] = bv0; tv[o + 1] = bv1; tv[o + 2] = bv2;
                ti[o] = bi0; ti[o + 1] = bi1; ti[o + 2] = bi2;
            }
        }
    }
}

// ---------- kernel 2: merge approx candidates, exact f32 rescore, context ----------
// one block (256 threads) per query
__global__ __launch_bounds__(256)
void merge_rescore_kernel(const float* __restrict__ tv, const int* __restrict__ ti,
                          const float* __restrict__ kb, const float* __restrict__ qunit,
                          float* __restrict__ ctx_out, int NB, int N) {
    __shared__ float sq[DIM];
    __shared__ float swv[4][3];
    __shared__ int   swi[4][3];
    __shared__ float s_tau;
    __shared__ int   s_cnt;
    __shared__ float cv[64];
    __shared__ int   ci[64];
    __shared__ int   fidx[3];

    const int q = blockIdx.x, t = threadIdx.x;
    if (t < DIM) sq[t] = qunit[(size_t)q * DIM + t];
    if (t == 0) s_cnt = 0;
    const float* tvq = tv + (size_t)q * NB * 3;
    const int*   tiq = ti + (size_t)q * NB * 3;
    const int total = NB * 3;

    // approx top-3 across all per-block candidates
    float v0 = NEG_HUGE, v1 = NEG_HUGE, v2 = NEG_HUGE;
    int   i0 = 0, i1 = 0, i2 = 0;
    for (int c = t; c < total; c += 256)
        ins3_cmp(tvq[c], tiq[c], v0, i0, v1, i1, v2, i2);
    #pragma unroll
    for (int off = 1; off < 64; off <<= 1) {
        float w0 = __shfl_xor(v0, off), w1 = __shfl_xor(v1, off), w2 = __shfl_xor(v2, off);
        int   x0 = __shfl_xor(i0, off), x1 = __shfl_xor(i1, off), x2 = __shfl_xor(i2, off);
        ins3_cmp(w0, x0, v0, i0, v1, i1, v2, i2);
        ins3_cmp(w1, x1, v0, i0, v1, i1, v2, i2);
        ins3_cmp(w2, x2, v0, i0, v1, i1, v2, i2);
    }
    if ((t & 63) == 0) {
        int wv = t >> 6;
        swv[wv][0] = v0; swv[wv][1] = v1; swv[wv][2] = v2;
        swi[wv][0] = i0; swi[wv][1] = i1; swi[wv][2] = i2;
    }
    __syncthreads();
    if (t == 0) {
        float a0 = NEG_HUGE, a1 = NEG_HUGE, a2 = NEG_HUGE;
        int   b0 = 0, b1 = 0, b2 = 0;
        for (int wv = 0; wv < 4; wv++)
            for (int r = 0; r < 3; r++)
                ins3_cmp(swv[wv][r], swi[wv][r], a0, b0, a1, b1, a2, b2);
        s_tau = a2 - 0.02f;    // margin >> bf16 approx error (~0.003)
    }
    __syncthreads();
    const float tau = s_tau;

    // exact f32 rescore of every candidate within the margin
    for (int c = t; c < total; c += 256) {
        float av = tvq[c];
        if (av >= tau) {
            int idx = tiq[c];
            const float4* kr = (const float4*)kb + (size_t)idx * 16;
            const float4* qr = (const float4*)sq;
            float dot = 0.f, ss = 0.f;
            #pragma unroll
            for (int d = 0; d < 16; d++) {
                float4 kv = kr[d], qv = qr[d];
                dot += kv.x * qv.x + kv.y * qv.y + kv.z * qv.z + kv.w * qv.w;
                ss  += kv.x * kv.x + kv.y * kv.y + kv.z * kv.z + kv.w * kv.w;
            }
            float ex = dot * ((ss > 0.f) ? (1.0f / sqrtf(ss)) : 1.0f);
            int slot = atomicAdd(&s_cnt, 1);
            if (slot < 64) { cv[slot] = ex; ci[slot] = idx; }
        }
    }
    __syncthreads();
    if (t == 0) {
        float f0 = NEG_HUGE, f1 = NEG_HUGE, f2 = NEG_HUGE;
        int   g0 = 0, g1 = 0, g2 = 0;
        int n = s_cnt < 64 ? s_cnt : 64;
        for (int c = 0; c < n; c++)
            ins3_cmp(cv[c], ci[c], f0, g0, f1, g1, f2, g2);
        fidx[0] = g0; fidx[1] = g1; fidx[2] = g2;
    }
    __syncthreads();
    if (t < DIM) {
        float c0 = kb[(size_t)fidx[0] * DIM + t];
        float c1 = kb[(size_t)fidx[1] * DIM + t];
        float c2 = kb[(size_t)fidx[2] * DIM + t];
        ctx_out[(size_t)q * DIM + t] = ((c0 + c1) + c2) / 3.0f;
    }
}

// ---------- kernel 3: MLP tail (attn == 1 identically; q/k are dead code) ----------
__global__ void mlp_kernel(const float* __restrict__ emb,
                           const float* __restrict__ ctx,
                           const float* __restrict__ in_proj_w,
                           const float* __restrict__ in_proj_b,
                           const float* __restrict__ out_w,
                           const float* __restrict__ out_b,
                           const float* __restrict__ ci_w1,
                           const float* __restrict__ ci_b1,
                           const float* __restrict__ ci_w2,
                           const float* __restrict__ ci_b2,
                           const float* __restrict__ cls_w1,
                           const float* __restrict__ cls_b1,
                           const float* __restrict__ cls_w2,
                           const float* __restrict__ cls_b2,
                           float* __restrict__ pred) {
    __shared__ float se[64], sc[64], sv[64], sa[64], sh[64], senh[64], scc[128];
    const int b = blockIdx.x, t = threadIdx.x;

    if (t < 64) { se[t] = emb[b * 64 + t]; sc[t] = ctx[b * 64 + t]; }
    __syncthreads();
    if (t < 64) {   // v = ctx @ wv.T + bv
        const float* w = in_proj_w + (size_t)(128 + t) * 64;
        float s = in_proj_b[128 + t];
        #pragma unroll 8
        for (int d = 0; d < 64; d++) s += sc[d] * w[d];
        sv[t] = s;
    }
    __syncthreads();
    if (t < 64) {   // attended = v @ out_w.T + out_b
        const float* w = out_w + (size_t)t * 64;
        float s = out_b[t];
        #pragma unroll 8
        for (int d = 0; d < 64; d++) s += sv[d] * w[d];
        sa[t] = s;
    }
    __syncthreads();
    if (t < 64) {   // h = relu([emb, attended] @ ci_w1.T + ci_b1)
        const float* w = ci_w1 + (size_t)t * 128;
        float s = ci_b1[t];
        #pragma unroll 8
        for (int d = 0; d < 64; d++) s += se[d] * w[d];
        #pragma unroll 8
        for (int d = 0; d < 64; d++) s += sa[d] * w[64 + d];
        sh[t] = fmaxf(s, 0.f);
    }
    __syncthreads();
    if (t < 64) {   // enhanced = h @ ci_w2.T + ci_b2
        const float* w = ci_w2 + (size_t)t * 64;
        float s = ci_b2[t];
        #pragma unroll 8
        for (int d = 0; d < 64; d++) s += sh[d] * w[d];
        senh[t] = s;
    }
    __syncthreads();
    {               // c = relu(enhanced @ cls_w1.T + cls_b1)
        const float* w = cls_w1 + (size_t)t * 64;
        float s = cls_b1[t];
        #pragma unroll 8
        for (int d = 0; d < 64; d++) s += senh[d] * w[d];
        scc[t] = fmaxf(s, 0.f);
    }
    __syncthreads();
    if (t < 2) {    // predictions = c @ cls_w2.T + cls_b2
        const float* w = cls_w2 + (size_t)t * 128;
        float s = cls_b2[t];
        for (int d = 0; d < 128; d++) s += scc[d] * w[d];
        pred[b * 2 + t] = s;
    }
}

extern "C" void kernel_launch(void* const* d_in, const int* in_sizes, int n_in,
                              void* d_out, int out_size, void* d_ws, size_t ws_size,
                              hipStream_t stream) {
    const float* emb       = (const float*)d_in[0];
    const float* kb        = (const float*)d_in[1];
    const float* in_proj_w = (const float*)d_in[2];
    const float* in_proj_b = (const float*)d_in[3];
    const float* out_w     = (const float*)d_in[4];
    const float* out_b     = (const float*)d_in[5];
    const float* ci_w1     = (const float*)d_in[6];
    const float* ci_b1     = (const float*)d_in[7];
    const float* ci_w2     = (const float*)d_in[8];
    const float* ci_b2     = (const float*)d_in[9];
    const float* cls_w1    = (const float*)d_in[10];
    const float* cls_b1    = (const float*)d_in[11];
    const float* cls_w2    = (const float*)d_in[12];
    const float* cls_b2    = (const float*)d_in[13];
    float* out = (float*)d_out;

    const int Bq = in_sizes[0] / DIM;   // 256
    const int N  = in_sizes[1] / DIM;   // 1,000,000

    // workspace: [qunit: Bq*64 f32][tv: Bq*NB*3 f32][ti: Bq*NB*3 i32]  (same as round-1)
    float* qunit = (float*)d_ws;
    const size_t qunit_bytes = (size_t)Bq * DIM * 4;
    long avail = (long)ws_size - (long)qunit_bytes;
    int NB = (int)(avail / ((long)Bq * 3 * 8));
    if (NB > 1024) NB = 1024;
    if (NB < 1)    NB = 1;
    float* tv = qunit + (size_t)Bq * DIM;
    int*   ti = (int*)(tv + (size_t)Bq * NB * 3);
    const int rpb = (N + NB - 1) / NB;   // NB>=245 keeps chunk count <= 64 (8-bit tag)

    float* ctx_out  = out + (size_t)Bq * 2;
    float* pred_out = out;

    qunit_kernel<<<Bq, 64, 0, stream>>>(emb, qunit);
    score_topk_kernel<<<NB, 256, 0, stream>>>(kb, qunit, tv, ti, NB, N, rpb);
    merge_rescore_kernel<<<Bq, 256, 0, stream>>>(tv, ti, kb, qunit, ctx_out, NB, N);
    mlp_kernel<<<Bq, 128, 0, stream>>>(emb, ctx_out, in_proj_w, in_proj_b,
                                       out_w, out_b, ci_w1, ci_b1, ci_w2, ci_b2,
                                       cls_w1, cls_b1, cls_w2, cls_b2, pred_out);
}